// Round 1
// baseline (634.650 us; speedup 1.0000x reference)
//
#include <hip/hip_runtime.h>

#define MARGIN 0.3f
#define BIGF 1e30f

constexpr int D = 256;

// ---------------- K0: row squared norms + init min buffers ----------------
__global__ __launch_bounds__(256)
void k0_sq_init(const float* __restrict__ E, float* __restrict__ sq,
                unsigned* __restrict__ minAll, unsigned* __restrict__ minSemi, int B) {
  int wave = threadIdx.x >> 6, lane = threadIdx.x & 63;
  int row = blockIdx.x * 4 + wave;
  if (row >= B) return;
  const float4 v = *(const float4*)&E[(size_t)row * D + lane * 4];
  float s = v.x * v.x + v.y * v.y + v.z * v.z + v.w * v.w;
#pragma unroll
  for (int off = 32; off; off >>= 1) s += __shfl_xor(s, off);
  if (lane == 0) {
    sq[row] = s;
    minAll[row] = __float_as_uint(BIGF);
    minSemi[row] = __float_as_uint(BIGF);
  }
}

// ---------------- K1: hardest positive per row (same-label pairs only) ----
__global__ __launch_bounds__(256)
void k1_dap(const float* __restrict__ E, const int* __restrict__ labels,
            const float* __restrict__ sq, float* __restrict__ d_ap,
            int* __restrict__ haspos, int B) {
  __shared__ float ei[D];
  __shared__ int list[1024];
  __shared__ int cnt;
  __shared__ float wmax[4];
  int i = blockIdx.x;
  int t = threadIdx.x;
  if (t == 0) cnt = 0;
  __syncthreads();
  ei[t] = E[(size_t)i * D + t];  // blockDim == D == 256
  int li = labels[i];
  for (int j = t; j < B; j += 256) {
    if (j != i && labels[j] == li) {
      int p = atomicAdd(&cnt, 1);
      if (p < 1024) list[p] = j;
    }
  }
  __syncthreads();
  int n = min(cnt, 1024);
  int wave = t >> 6, lane = t & 63;
  float m = -BIGF;
  float sqi = sq[i];
  for (int p = wave; p < n; p += 4) {
    int j = list[p];
    float4 a = *(const float4*)&ei[lane * 4];
    float4 b = *(const float4*)&E[(size_t)j * D + lane * 4];
    float s = a.x * b.x + a.y * b.y + a.z * b.z + a.w * b.w;
#pragma unroll
    for (int off = 32; off; off >>= 1) s += __shfl_xor(s, off);
    float dd = fmaxf(sqi + sq[j] - 2.f * s, 0.f);
    m = fmaxf(m, dd);
  }
  if (lane == 0) wmax[wave] = m;
  __syncthreads();
  if (t == 0) {
    float mm = fmaxf(fmaxf(wmax[0], wmax[1]), fmaxf(wmax[2], wmax[3]));
    d_ap[i] = (n > 0) ? mm : -BIGF;
    haspos[i] = (n > 0) ? 1 : 0;
  }
}

// ---------------- K2: full Gram pass with fused masked-min epilogue -------
#define BI 64
#define BJ 64
#define BK 64
#define LDW (BI + 4)  // 68 floats -> 272B rows, 16B aligned

__global__ __launch_bounds__(256, 4)
void k2_main(const float* __restrict__ E, const int* __restrict__ labels,
             const float* __restrict__ sq, const float* __restrict__ d_ap,
             unsigned* __restrict__ minAll, unsigned* __restrict__ minSemi,
             int B, int splitJ) {
  __shared__ float As[BK][LDW];
  __shared__ float Bs[BK][LDW];
  __shared__ float sqj[BJ];
  __shared__ int labj[BJ];

  const int tid = threadIdx.x;
  const int tx = tid & 15, ty = tid >> 4;
  const int iT = blockIdx.x / splitJ;
  const int sp = blockIdx.x % splitJ;
  const int iBase = iT * BI;
  const int jSpan = B / splitJ;
  const int jBeg = sp * jSpan;

  float sqi[4], dap[4];
  int labi[4];
  float mAll[4], mSemi[4];
#pragma unroll
  for (int ii = 0; ii < 4; ++ii) {
    int gi = iBase + ty * 4 + ii;
    sqi[ii] = sq[gi];
    labi[ii] = labels[gi];
    dap[ii] = d_ap[gi];
    mAll[ii] = BIGF;
    mSemi[ii] = BIGF;
  }

  for (int jt = 0; jt < jSpan / BJ; ++jt) {
    const int jBase = jBeg + jt * BJ;
    __syncthreads();  // prev epilogue reads of sqj/labj done
    if (tid < BJ) { sqj[tid] = sq[jBase + tid]; labj[tid] = labels[jBase + tid]; }
    float acc[4][4] = {};
    for (int kt = 0; kt < D / BK; ++kt) {
      const int k0 = kt * BK;
      // transpose-store A and B chunks with XOR swizzle col = row ^ ((k>>2)&7)
#pragma unroll
      for (int r = 0; r < 4; ++r) {
        int f = tid + 256 * r;
        int row = f >> 4;          // 0..63
        int m = f & 15;
        int kk = m << 2;           // 0,4,...,60
        float4 av = *(const float4*)&E[(size_t)(iBase + row) * D + k0 + kk];
        float4 bv = *(const float4*)&E[(size_t)(jBase + row) * D + k0 + kk];
        int col = row ^ (m & 7);
        As[kk + 0][col] = av.x; As[kk + 1][col] = av.y;
        As[kk + 2][col] = av.z; As[kk + 3][col] = av.w;
        Bs[kk + 0][col] = bv.x; Bs[kk + 1][col] = bv.y;
        Bs[kk + 2][col] = bv.z; Bs[kk + 3][col] = bv.w;
      }
      __syncthreads();
#pragma unroll
      for (int k = 0; k < BK; ++k) {
        const int sz = (k >> 2) & 7;
        const int s4 = sz & 4, s3 = sz & 3;
        float4 af = *(const float4*)&As[k][(ty * 4) ^ s4];
        float4 bf = *(const float4*)&Bs[k][(tx * 4) ^ s4];
        float av[4] = {af.x, af.y, af.z, af.w};
        float bv[4] = {bf.x, bf.y, bf.z, bf.w};
#pragma unroll
        for (int ii = 0; ii < 4; ++ii)
#pragma unroll
          for (int jj = 0; jj < 4; ++jj)
            acc[ii][jj] = fmaf(av[ii ^ s3], bv[jj ^ s3], acc[ii][jj]);
      }
      __syncthreads();  // reads done before next kt's writes
    }
    // fused epilogue: masked running minima
#pragma unroll
    for (int ii = 0; ii < 4; ++ii) {
#pragma unroll
      for (int jj = 0; jj < 4; ++jj) {
        int jl = tx * 4 + jj;
        float dd = fmaxf(sqi[ii] + sqj[jl] - 2.f * acc[ii][jj], 0.f);
        if (labj[jl] != labi[ii]) {
          mAll[ii] = fminf(mAll[ii], dd);
          if (dd > dap[ii] && dd < dap[ii] + MARGIN) mSemi[ii] = fminf(mSemi[ii], dd);
        }
      }
    }
  }
  // reduce across the 16 tx lanes (same ty -> 16 consecutive lanes in wave)
#pragma unroll
  for (int ii = 0; ii < 4; ++ii) {
#pragma unroll
    for (int off = 1; off < 16; off <<= 1) {
      mAll[ii] = fminf(mAll[ii], __shfl_xor(mAll[ii], off));
      mSemi[ii] = fminf(mSemi[ii], __shfl_xor(mSemi[ii], off));
    }
  }
  if (tx == 0) {
#pragma unroll
    for (int ii = 0; ii < 4; ++ii) {
      int gi = iBase + ty * 4 + ii;
      atomicMin(&minAll[gi], __float_as_uint(mAll[ii]));
      atomicMin(&minSemi[gi], __float_as_uint(mSemi[ii]));
    }
  }
}

// ---------------- K3: deterministic final reduction -----------------------
__global__ __launch_bounds__(256)
void k3_final(const float* __restrict__ d_ap, const int* __restrict__ haspos,
              const unsigned* __restrict__ minAll, const unsigned* __restrict__ minSemi,
              float* __restrict__ out, int B) {
  __shared__ float ssum[256];
  __shared__ int scnt[256];
  int t = threadIdx.x;
  float lsum = 0.f;
  int lcnt = 0;
  for (int i = t; i < B; i += 256) {
    float mA = __uint_as_float(minAll[i]);
    float mS = __uint_as_float(minSemi[i]);
    float dan = (mS < 1e29f) ? mS : mA;
    float loss = fmaxf(d_ap[i] - dan + MARGIN, 0.f);
    if (haspos[i]) { lsum += loss; lcnt += 1; }
  }
  ssum[t] = lsum;
  scnt[t] = lcnt;
  __syncthreads();
  for (int off = 128; off; off >>= 1) {
    if (t < off) { ssum[t] += ssum[t + off]; scnt[t] += scnt[t + off]; }
    __syncthreads();
  }
  if (t == 0) out[0] = ssum[0] / (float)max(scnt[0], 1);
}

extern "C" void kernel_launch(void* const* d_in, const int* in_sizes, int n_in,
                              void* d_out, int out_size, void* d_ws, size_t ws_size,
                              hipStream_t stream) {
  const float* E = (const float*)d_in[0];
  const int* labels = (const int*)d_in[1];
  int B = in_sizes[1];

  float* ws = (float*)d_ws;
  float* sq = ws;              // [B]
  float* dap = ws + B;         // [B]
  int* haspos = (int*)(ws + 2 * B);        // [B]
  unsigned* minAll = (unsigned*)(ws + 3 * B);   // [B]
  unsigned* minSemi = (unsigned*)(ws + 4 * B);  // [B]
  float* out = (float*)d_out;

  k0_sq_init<<<(B + 3) / 4, 256, 0, stream>>>(E, sq, minAll, minSemi, B);
  k1_dap<<<B, 256, 0, stream>>>(E, labels, sq, dap, haspos, B);
  const int splitJ = 4;
  k2_main<<<(B / BI) * splitJ, 256, 0, stream>>>(E, labels, sq, dap, minAll, minSemi, B, splitJ);
  k3_final<<<1, 256, 0, stream>>>(dap, haspos, minAll, minSemi, out, B);
}

// Round 2
// 289.034 us; speedup vs baseline: 2.1958x; 2.1958x over previous
//
#include <hip/hip_runtime.h>

#define MARGIN 0.3f
#define BIGF 1e30f

constexpr int D = 256;

typedef __attribute__((ext_vector_type(8))) short bf16x8;
typedef __attribute__((ext_vector_type(4))) float f32x4;

__device__ __forceinline__ unsigned short f2bf(float f) {
  unsigned u = __float_as_uint(f);
  unsigned r = (u + 0x7fffu + ((u >> 16) & 1u)) >> 16;
  return (unsigned short)r;
}
__device__ __forceinline__ float bf2f(unsigned short h) {
  return __uint_as_float(((unsigned)h) << 16);
}

__device__ __forceinline__ void gll16(const void* g, void* l) {
  __builtin_amdgcn_global_load_lds(
      (const __attribute__((address_space(1))) unsigned int*)g,
      (__attribute__((address_space(3))) unsigned int*)l, 16, 0, 0);
}

// ---------------- K0: row squared norms + init min buffers ----------------
__global__ __launch_bounds__(256)
void k0_sq_init(const float* __restrict__ E, float* __restrict__ sq,
                unsigned* __restrict__ minAll, unsigned* __restrict__ minSemi, int B) {
  int wave = threadIdx.x >> 6, lane = threadIdx.x & 63;
  int row = blockIdx.x * 4 + wave;
  if (row >= B) return;
  const float4 v = *(const float4*)&E[(size_t)row * D + lane * 4];
  float s = v.x * v.x + v.y * v.y + v.z * v.z + v.w * v.w;
#pragma unroll
  for (int off = 32; off; off >>= 1) s += __shfl_xor(s, off);
  if (lane == 0) {
    sq[row] = s;
    minAll[row] = __float_as_uint(BIGF);
    minSemi[row] = __float_as_uint(BIGF);
  }
}

// ---------------- Ksplit: E -> (hi, lo) bf16 pair -------------------------
__global__ __launch_bounds__(256)
void k_split(const float* __restrict__ E, unsigned short* __restrict__ hi,
             unsigned short* __restrict__ lo, int n4) {
  int idx = blockIdx.x * 256 + threadIdx.x;
  if (idx >= n4) return;
  float4 v = ((const float4*)E)[idx];
  ushort4 h, l;
  h.x = f2bf(v.x); l.x = f2bf(v.x - bf2f(h.x));
  h.y = f2bf(v.y); l.y = f2bf(v.y - bf2f(h.y));
  h.z = f2bf(v.z); l.z = f2bf(v.z - bf2f(h.z));
  h.w = f2bf(v.w); l.w = f2bf(v.w - bf2f(h.w));
  ((ushort4*)hi)[idx] = h;
  ((ushort4*)lo)[idx] = l;
}

// ---------------- K1: hardest positive per row (same-label pairs only) ----
__global__ __launch_bounds__(256)
void k1_dap(const float* __restrict__ E, const int* __restrict__ labels,
            const float* __restrict__ sq, float* __restrict__ d_ap,
            int* __restrict__ haspos, int B) {
  __shared__ float ei[D];
  __shared__ int list[1024];
  __shared__ int cnt;
  __shared__ float wmax[4];
  int i = blockIdx.x;
  int t = threadIdx.x;
  if (t == 0) cnt = 0;
  __syncthreads();
  ei[t] = E[(size_t)i * D + t];
  int li = labels[i];
  for (int j = t; j < B; j += 256) {
    if (j != i && labels[j] == li) {
      int p = atomicAdd(&cnt, 1);
      if (p < 1024) list[p] = j;
    }
  }
  __syncthreads();
  int n = min(cnt, 1024);
  int wave = t >> 6, lane = t & 63;
  float m = -BIGF;
  float sqi = sq[i];
  for (int p = wave; p < n; p += 4) {
    int j = list[p];
    float4 a = *(const float4*)&ei[lane * 4];
    float4 b = *(const float4*)&E[(size_t)j * D + lane * 4];
    float s = a.x * b.x + a.y * b.y + a.z * b.z + a.w * b.w;
#pragma unroll
    for (int off = 32; off; off >>= 1) s += __shfl_xor(s, off);
    float dd = fmaxf(sqi + sq[j] - 2.f * s, 0.f);
    m = fmaxf(m, dd);
  }
  if (lane == 0) wmax[wave] = m;
  __syncthreads();
  if (t == 0) {
    float mm = fmaxf(fmaxf(wmax[0], wmax[1]), fmaxf(wmax[2], wmax[3]));
    d_ap[i] = (n > 0) ? mm : -BIGF;
    haspos[i] = (n > 0) ? 1 : 0;
  }
}

// ---------------- K2: bf16 split MFMA Gram + fused masked-min epilogue ----
// C = Ehi*Ehi^T + Ehi*Elo^T + Elo*Ehi^T  (virtual K = 768, BK = 64 -> 12 kt)
// 128x128 tile, 4 waves (2x2 of 64x64), 16x16x32 bf16 MFMA, m97 structure.
__global__ __launch_bounds__(256)
void k2_mfma(const unsigned short* __restrict__ Ehi, const unsigned short* __restrict__ Elo,
             const int* __restrict__ labels, const float* __restrict__ sq,
             const float* __restrict__ d_ap,
             unsigned* __restrict__ minAll, unsigned* __restrict__ minSemi, int B) {
  __shared__ unsigned short Ast[128][64];
  __shared__ unsigned short Bst[128][64];
  __shared__ float sqI[128], sqJ[128], dapI[128];
  __shared__ int labI[128], labJ[128];
  __shared__ unsigned smAll[128], smSemi[128];

  const int tid = threadIdx.x;
  const int lane = tid & 63;
  const int wave = tid >> 6;
  const int wr = wave >> 1, wc = wave & 1;
  const int lo4 = lane & 15, hi4 = lane >> 4;

  // XCD-aware swizzle (nwg = 4096, divisible by 8)
  const int nwg = gridDim.x;
  const int bid = blockIdx.x;
  const int swz = (bid & 7) * (nwg >> 3) + (bid >> 3);
  const int iBase = (swz >> 6) * 128;
  const int jBase = (swz & 63) * 128;

  if (tid < 128) {
    int gi = iBase + tid, gj = jBase + tid;
    sqI[tid] = sq[gi]; labI[tid] = labels[gi]; dapI[tid] = d_ap[gi];
    sqJ[tid] = sq[gj]; labJ[tid] = labels[gj];
    smAll[tid] = __float_as_uint(BIGF);
    smSemi[tid] = __float_as_uint(BIGF);
  }

  f32x4 acc[4][4];
#pragma unroll
  for (int m = 0; m < 4; ++m)
#pragma unroll
    for (int n = 0; n < 4; ++n) acc[m][n] = (f32x4){0.f, 0.f, 0.f, 0.f};

  const int wbase = tid & 192;  // wave-uniform thread base

  for (int kt = 0; kt < 12; ++kt) {
    const int seg = kt >> 2;
    const int k0 = (kt & 3) * 64;
    const unsigned short* aSrc = (seg == 2) ? Elo : Ehi;
    const unsigned short* bSrc = (seg == 1) ? Elo : Ehi;
    __syncthreads();  // previous compute's LDS reads done
#pragma unroll
    for (int p = 0; p < 4; ++p) {
      int f = p * 256 + tid;        // 0..1023 ; covers 128 rows x 8 chunks of 8 bf16
      int row = f >> 3;
      int ch = f & 7;
      unsigned short* lA = &Ast[0][0] + (size_t)(p * 256 + wbase) * 8;
      unsigned short* lB = &Bst[0][0] + (size_t)(p * 256 + wbase) * 8;
      gll16(aSrc + (size_t)(iBase + row) * D + k0 + ch * 8, lA);
      gll16(bSrc + (size_t)(jBase + row) * D + k0 + ch * 8, lB);
    }
    __syncthreads();  // drains vmcnt before barrier -> staged data visible
#pragma unroll
    for (int ks = 0; ks < 2; ++ks) {
      bf16x8 aF[4], bF[4];
#pragma unroll
      for (int m = 0; m < 4; ++m)
        aF[m] = *(const bf16x8*)&Ast[wr * 64 + m * 16 + lo4][ks * 32 + hi4 * 8];
#pragma unroll
      for (int n = 0; n < 4; ++n)
        bF[n] = *(const bf16x8*)&Bst[wc * 64 + n * 16 + lo4][ks * 32 + hi4 * 8];
#pragma unroll
      for (int m = 0; m < 4; ++m)
#pragma unroll
        for (int n = 0; n < 4; ++n)
          acc[m][n] = __builtin_amdgcn_mfma_f32_16x16x32_bf16(aF[m], bF[n], acc[m][n], 0, 0, 0);
    }
  }

  __syncthreads();  // epilogue shared arrays ready; compute done
#pragma unroll
  for (int m = 0; m < 4; ++m) {
#pragma unroll
    for (int reg = 0; reg < 4; ++reg) {
      const int li = wr * 64 + m * 16 + hi4 * 4 + reg;
      const float si = sqI[li], da = dapI[li];
      const int lbi = labI[li];
      float rAll = BIGF, rSemi = BIGF;
#pragma unroll
      for (int n = 0; n < 4; ++n) {
        const int lj = wc * 64 + n * 16 + lo4;
        float dd = fmaxf(si + sqJ[lj] - 2.f * acc[m][n][reg], 0.f);
        if (labJ[lj] != lbi) {
          rAll = fminf(rAll, dd);
          if (dd > da && dd < da + MARGIN) rSemi = fminf(rSemi, dd);
        }
      }
#pragma unroll
      for (int off = 1; off < 16; off <<= 1) {
        rAll = fminf(rAll, __shfl_xor(rAll, off));
        rSemi = fminf(rSemi, __shfl_xor(rSemi, off));
      }
      if (lo4 == 0) {
        atomicMin(&smAll[li], __float_as_uint(rAll));
        atomicMin(&smSemi[li], __float_as_uint(rSemi));
      }
    }
  }
  __syncthreads();
  if (tid < 128) {
    atomicMin(&minAll[iBase + tid], smAll[tid]);
    atomicMin(&minSemi[iBase + tid], smSemi[tid]);
  }
}

// ---------------- K3: deterministic final reduction -----------------------
__global__ __launch_bounds__(256)
void k3_final(const float* __restrict__ d_ap, const int* __restrict__ haspos,
              const unsigned* __restrict__ minAll, const unsigned* __restrict__ minSemi,
              float* __restrict__ out, int B) {
  __shared__ float ssum[256];
  __shared__ int scnt[256];
  int t = threadIdx.x;
  float lsum = 0.f;
  int lcnt = 0;
  for (int i = t; i < B; i += 256) {
    float mA = __uint_as_float(minAll[i]);
    float mS = __uint_as_float(minSemi[i]);
    float dan = (mS < 1e29f) ? mS : mA;
    float loss = fmaxf(d_ap[i] - dan + MARGIN, 0.f);
    if (haspos[i]) { lsum += loss; lcnt += 1; }
  }
  ssum[t] = lsum;
  scnt[t] = lcnt;
  __syncthreads();
  for (int off = 128; off; off >>= 1) {
    if (t < off) { ssum[t] += ssum[t + off]; scnt[t] += scnt[t + off]; }
    __syncthreads();
  }
  if (t == 0) out[0] = ssum[0] / (float)max(scnt[0], 1);
}

extern "C" void kernel_launch(void* const* d_in, const int* in_sizes, int n_in,
                              void* d_out, int out_size, void* d_ws, size_t ws_size,
                              hipStream_t stream) {
  const float* E = (const float*)d_in[0];
  const int* labels = (const int*)d_in[1];
  int B = in_sizes[1];

  float* ws = (float*)d_ws;
  float* sq = ws;                               // [B]
  float* dap = ws + B;                          // [B]
  int* haspos = (int*)(ws + 2 * B);             // [B]
  unsigned* minAll = (unsigned*)(ws + 3 * B);   // [B]
  unsigned* minSemi = (unsigned*)(ws + 4 * B);  // [B]
  unsigned short* Ehi = (unsigned short*)(ws + 5 * B);        // [B*D] bf16
  unsigned short* Elo = Ehi + (size_t)B * D;                  // [B*D] bf16
  float* out = (float*)d_out;

  k0_sq_init<<<(B + 3) / 4, 256, 0, stream>>>(E, sq, minAll, minSemi, B);
  int n4 = B * D / 4;
  k_split<<<(n4 + 255) / 256, 256, 0, stream>>>(E, Ehi, Elo, n4);
  k1_dap<<<B, 256, 0, stream>>>(E, labels, sq, dap, haspos, B);
  int tiles = B / 128;
  k2_mfma<<<tiles * tiles, 256, 0, stream>>>(Ehi, Elo, labels, sq, dap, minAll, minSemi, B);
  k3_final<<<1, 256, 0, stream>>>(dap, haspos, minAll, minSemi, out, B);
}

// Round 3
// 167.835 us; speedup vs baseline: 3.7814x; 1.7221x over previous
//
#include <hip/hip_runtime.h>

#define MARGIN 0.3f
#define BIGF 1e30f
#define MAXC 64

constexpr int D = 256;

typedef __attribute__((ext_vector_type(8))) short bf16x8;
typedef __attribute__((ext_vector_type(4))) float f32x4;

__device__ __forceinline__ unsigned short f2bf(float f) {
  unsigned u = __float_as_uint(f);
  unsigned r = (u + 0x7fffu + ((u >> 16) & 1u)) >> 16;
  return (unsigned short)r;
}
__device__ __forceinline__ float bf2f(unsigned short h) {
  return __uint_as_float(((unsigned)h) << 16);
}

__device__ __forceinline__ void gll16(const void* g, void* l) {
  __builtin_amdgcn_global_load_lds(
      (const __attribute__((address_space(1))) unsigned int*)g,
      (__attribute__((address_space(3))) unsigned int*)l, 16, 0, 0);
}

// ---- K0: fused row-norm + bf16 hi/lo split + min-buffer init + cnt zero ----
__global__ __launch_bounds__(256)
void k0_split(const float* __restrict__ E, unsigned short* __restrict__ hi,
              unsigned short* __restrict__ lo, float* __restrict__ sq,
              unsigned* __restrict__ minAll, unsigned* __restrict__ minSemi,
              int* __restrict__ cnt, int B) {
  if (blockIdx.x == 0) {
    for (int c = threadIdx.x; c < 512; c += 256) cnt[c] = 0;
  }
  int wave = threadIdx.x >> 6, lane = threadIdx.x & 63;
  int row = blockIdx.x * 4 + wave;
  if (row >= B) return;
  float4 v = *(const float4*)&E[(size_t)row * D + lane * 4];
  ushort4 h, l;
  h.x = f2bf(v.x); l.x = f2bf(v.x - bf2f(h.x));
  h.y = f2bf(v.y); l.y = f2bf(v.y - bf2f(h.y));
  h.z = f2bf(v.z); l.z = f2bf(v.z - bf2f(h.z));
  h.w = f2bf(v.w); l.w = f2bf(v.w - bf2f(h.w));
  *(ushort4*)&hi[(size_t)row * D + lane * 4] = h;
  *(ushort4*)&lo[(size_t)row * D + lane * 4] = l;
  float s = v.x * v.x + v.y * v.y + v.z * v.z + v.w * v.w;
#pragma unroll
  for (int off = 32; off; off >>= 1) s += __shfl_xor(s, off);
  if (lane == 0) {
    sq[row] = s;
    minAll[row] = __float_as_uint(BIGF);
    minSemi[row] = __float_as_uint(BIGF);
  }
}

// ---- KB: class buckets (order within bucket nondeterministic; max is
//          order-independent, so d_ap is still deterministic) ----
__global__ __launch_bounds__(256)
void kb_fill(const int* __restrict__ labels, int* __restrict__ cnt,
             int* __restrict__ members, int B) {
  int i = blockIdx.x * 256 + threadIdx.x;
  if (i >= B) return;
  int lab = labels[i];
  int p = atomicAdd(&cnt[lab], 1);
  if (p < MAXC) members[lab * MAXC + p] = i;
}

// ---- K1: hardest positive per row via bucket list (one wave per row) ----
__global__ __launch_bounds__(256)
void k1_dap(const float* __restrict__ E, const int* __restrict__ labels,
            const float* __restrict__ sq, const int* __restrict__ cnt,
            const int* __restrict__ members, float* __restrict__ d_ap,
            int* __restrict__ haspos, int B) {
  int wave = threadIdx.x >> 6, lane = threadIdx.x & 63;
  int i = blockIdx.x * 4 + wave;
  if (i >= B) return;
  float4 a = *(const float4*)&E[(size_t)i * D + lane * 4];
  int li = labels[i];
  int n = min(cnt[li], MAXC);
  float sqi = sq[i];
  float m = -BIGF;
  for (int p = 0; p < n; ++p) {
    int j = members[li * MAXC + p];
    if (j == i) continue;
    float4 b = *(const float4*)&E[(size_t)j * D + lane * 4];
    float s = a.x * b.x + a.y * b.y + a.z * b.z + a.w * b.w;
#pragma unroll
    for (int off = 32; off; off >>= 1) s += __shfl_xor(s, off);
    m = fmaxf(m, fmaxf(sqi + sq[j] - 2.f * s, 0.f));
  }
  if (lane == 0) {
    d_ap[i] = (n > 1) ? m : -BIGF;
    haspos[i] = (n > 1) ? 1 : 0;
  }
}

// ---- K2: SYMMETRIC split-bf16 MFMA Gram, lower-triangle tiles -------------
// dot = hi*hi^T + hi*lo^T + lo*hi^T, all into one accumulator.
// Per block: 128x128 tile at (ti,tj), tj<=ti. Epilogue updates minima for
// BOTH i-rows (reduce over lo4 lanes) and j-rows (reduce over hi4 groups).
__global__ __launch_bounds__(256)
void k2_sym(const unsigned short* __restrict__ Ehi, const unsigned short* __restrict__ Elo,
            const float* __restrict__ sq, const float* __restrict__ d_ap,
            const int* __restrict__ labels,
            unsigned* __restrict__ minAll, unsigned* __restrict__ minSemi, int T) {
  __shared__ unsigned short Ah[128][64], Al[128][64], Bh[128][64], Bl[128][64];
  __shared__ float sqI[128], sqJ[128], dapI[128], dapJ[128];
  __shared__ int labI[128], labJ[128];
  __shared__ unsigned smAI[128], smSI[128], smAJ[128], smSJ[128];

  const int tid = threadIdx.x;
  const int lane = tid & 63;
  const int wave = tid >> 6;
  const int wr = wave >> 1, wc = wave & 1;
  const int lo4 = lane & 15, hi4 = lane >> 4;
  const int wbase = tid & 192;

  const int nwg = gridDim.x;
  const int bid = blockIdx.x;
  const int swz = ((nwg & 7) == 0) ? (bid & 7) * (nwg >> 3) + (bid >> 3) : bid;
  // triangle decode: swz = ti*(ti+1)/2 + tj, 0 <= tj <= ti < T
  int ti = (int)((sqrtf(8.f * (float)swz + 1.f) - 1.f) * 0.5f);
  while ((ti + 1) * (ti + 2) / 2 <= swz) ++ti;
  while (ti * (ti + 1) / 2 > swz) --ti;
  const int tj = swz - ti * (ti + 1) / 2;
  const int iBase = ti * 128, jBase = tj * 128;

  if (tid < 128) {
    int gi = iBase + tid, gj = jBase + tid;
    sqI[tid] = sq[gi]; labI[tid] = labels[gi]; dapI[tid] = d_ap[gi];
    sqJ[tid] = sq[gj]; labJ[tid] = labels[gj]; dapJ[tid] = d_ap[gj];
    smAI[tid] = smSI[tid] = smAJ[tid] = smSJ[tid] = __float_as_uint(BIGF);
  }

  f32x4 acc[4][4];
#pragma unroll
  for (int m = 0; m < 4; ++m)
#pragma unroll
    for (int n = 0; n < 4; ++n) acc[m][n] = (f32x4){0.f, 0.f, 0.f, 0.f};

  for (int kt = 0; kt < D / 64; ++kt) {
    const int k0 = kt * 64;
    __syncthreads();  // previous compute's LDS reads done
#pragma unroll
    for (int p = 0; p < 4; ++p) {
      int f = p * 256 + tid;
      int row = f >> 3, ch = f & 7;
      size_t sI = (size_t)(iBase + row) * D + k0 + ch * 8;
      size_t sJ = (size_t)(jBase + row) * D + k0 + ch * 8;
      size_t lOff = (size_t)(p * 256 + wbase) * 8;
      gll16(Ehi + sI, &Ah[0][0] + lOff);
      gll16(Elo + sI, &Al[0][0] + lOff);
      gll16(Ehi + sJ, &Bh[0][0] + lOff);
      gll16(Elo + sJ, &Bl[0][0] + lOff);
    }
    __syncthreads();  // vmcnt drained before barrier -> staged data visible
#pragma unroll
    for (int ks = 0; ks < 2; ++ks) {
      bf16x8 ah[4], al[4], bh[4], bl[4];
#pragma unroll
      for (int m = 0; m < 4; ++m) {
        ah[m] = *(const bf16x8*)&Ah[wr * 64 + m * 16 + lo4][ks * 32 + hi4 * 8];
        al[m] = *(const bf16x8*)&Al[wr * 64 + m * 16 + lo4][ks * 32 + hi4 * 8];
      }
#pragma unroll
      for (int n = 0; n < 4; ++n) {
        bh[n] = *(const bf16x8*)&Bh[wc * 64 + n * 16 + lo4][ks * 32 + hi4 * 8];
        bl[n] = *(const bf16x8*)&Bl[wc * 64 + n * 16 + lo4][ks * 32 + hi4 * 8];
      }
#pragma unroll
      for (int m = 0; m < 4; ++m)
#pragma unroll
        for (int n = 0; n < 4; ++n) {
          acc[m][n] = __builtin_amdgcn_mfma_f32_16x16x32_bf16(ah[m], bh[n], acc[m][n], 0, 0, 0);
          acc[m][n] = __builtin_amdgcn_mfma_f32_16x16x32_bf16(ah[m], bl[n], acc[m][n], 0, 0, 0);
          acc[m][n] = __builtin_amdgcn_mfma_f32_16x16x32_bf16(al[m], bh[n], acc[m][n], 0, 0, 0);
        }
    }
  }

  __syncthreads();
  // ---- row-side epilogue: anchors = i-rows, candidates = j-cols ----
#pragma unroll
  for (int m = 0; m < 4; ++m) {
#pragma unroll
    for (int reg = 0; reg < 4; ++reg) {
      const int li = wr * 64 + m * 16 + hi4 * 4 + reg;
      const float si = sqI[li], da = dapI[li];
      const int lbi = labI[li];
      float rA = BIGF, rS = BIGF;
#pragma unroll
      for (int n = 0; n < 4; ++n) {
        const int lj = wc * 64 + n * 16 + lo4;
        float dd = fmaxf(si + sqJ[lj] - 2.f * acc[m][n][reg], 0.f);
        if (labJ[lj] != lbi) {
          rA = fminf(rA, dd);
          if (dd > da && dd < da + MARGIN) rS = fminf(rS, dd);
        }
      }
#pragma unroll
      for (int off = 1; off < 16; off <<= 1) {
        rA = fminf(rA, __shfl_xor(rA, off));
        rS = fminf(rS, __shfl_xor(rS, off));
      }
      if (lo4 == 0) {
        atomicMin(&smAI[li], __float_as_uint(rA));
        atomicMin(&smSI[li], __float_as_uint(rS));
      }
    }
  }
  // ---- col-side epilogue: anchors = j-rows, candidates = i-cols ----
#pragma unroll
  for (int n = 0; n < 4; ++n) {
    const int lj = wc * 64 + n * 16 + lo4;
    const float sj = sqJ[lj], dj = dapJ[lj];
    const int lbj = labJ[lj];
    float cA = BIGF, cS = BIGF;
#pragma unroll
    for (int m = 0; m < 4; ++m)
#pragma unroll
      for (int reg = 0; reg < 4; ++reg) {
        const int li = wr * 64 + m * 16 + hi4 * 4 + reg;
        float dd = fmaxf(sqI[li] + sj - 2.f * acc[m][n][reg], 0.f);
        if (labI[li] != lbj) {
          cA = fminf(cA, dd);
          if (dd > dj && dd < dj + MARGIN) cS = fminf(cS, dd);
        }
      }
    cA = fminf(cA, __shfl_xor(cA, 16));
    cS = fminf(cS, __shfl_xor(cS, 16));
    cA = fminf(cA, __shfl_xor(cA, 32));
    cS = fminf(cS, __shfl_xor(cS, 32));
    if (hi4 == 0) {
      atomicMin(&smAJ[lj], __float_as_uint(cA));
      atomicMin(&smSJ[lj], __float_as_uint(cS));
    }
  }
  __syncthreads();
  if (tid < 128) {
    atomicMin(&minAll[iBase + tid], smAI[tid]);
    atomicMin(&minSemi[iBase + tid], smSI[tid]);
    atomicMin(&minAll[jBase + tid], smAJ[tid]);
    atomicMin(&minSemi[jBase + tid], smSJ[tid]);
  }
}

// ---- K3: deterministic final reduction ----
__global__ __launch_bounds__(256)
void k3_final(const float* __restrict__ d_ap, const int* __restrict__ haspos,
              const unsigned* __restrict__ minAll, const unsigned* __restrict__ minSemi,
              float* __restrict__ out, int B) {
  __shared__ float ssum[256];
  __shared__ int scnt[256];
  int t = threadIdx.x;
  float lsum = 0.f;
  int lcnt = 0;
  for (int i = t; i < B; i += 256) {
    float mA = __uint_as_float(minAll[i]);
    float mS = __uint_as_float(minSemi[i]);
    float dan = (mS < 1e29f) ? mS : mA;
    float loss = fmaxf(d_ap[i] - dan + MARGIN, 0.f);
    if (haspos[i]) { lsum += loss; lcnt += 1; }
  }
  ssum[t] = lsum;
  scnt[t] = lcnt;
  __syncthreads();
  for (int off = 128; off; off >>= 1) {
    if (t < off) { ssum[t] += ssum[t + off]; scnt[t] += scnt[t + off]; }
    __syncthreads();
  }
  if (t == 0) out[0] = ssum[0] / (float)max(scnt[0], 1);
}

extern "C" void kernel_launch(void* const* d_in, const int* in_sizes, int n_in,
                              void* d_out, int out_size, void* d_ws, size_t ws_size,
                              hipStream_t stream) {
  const float* E = (const float*)d_in[0];
  const int* labels = (const int*)d_in[1];
  int B = in_sizes[1];

  float* ws = (float*)d_ws;
  float* sq = ws;                                   // [B]
  float* dap = ws + B;                              // [B]
  int* haspos = (int*)(ws + 2 * B);                 // [B]
  unsigned* minAll = (unsigned*)(ws + 3 * B);       // [B]
  unsigned* minSemi = (unsigned*)(ws + 4 * B);      // [B]
  int* cnt = (int*)(ws + 5 * B);                    // [512]
  int* members = cnt + 512;                         // [512*MAXC]
  unsigned short* Ehi = (unsigned short*)(members + 512 * MAXC);  // [B*D] bf16
  unsigned short* Elo = Ehi + (size_t)B * D;                      // [B*D] bf16
  float* out = (float*)d_out;

  k0_split<<<(B + 3) / 4, 256, 0, stream>>>(E, Ehi, Elo, sq, minAll, minSemi, cnt, B);
  kb_fill<<<(B + 255) / 256, 256, 0, stream>>>(labels, cnt, members, B);
  k1_dap<<<(B + 3) / 4, 256, 0, stream>>>(E, labels, sq, cnt, members, dap, haspos, B);
  int T = B / 128;
  int nwg = T * (T + 1) / 2;
  k2_sym<<<nwg, 256, 0, stream>>>(Ehi, Elo, sq, dap, labels, minAll, minSemi, T);
  k3_final<<<1, 256, 0, stream>>>(dap, haspos, minAll, minSemi, out, B);
}

// Round 4
// 148.466 us; speedup vs baseline: 4.2747x; 1.1305x over previous
//
#include <hip/hip_runtime.h>

#define MARGIN 0.3f
#define BIGF 1e30f
#define MAXC 64

constexpr int D = 256;

typedef __attribute__((ext_vector_type(8))) short bf16x8;
typedef __attribute__((ext_vector_type(4))) float f32x4;

__device__ __forceinline__ unsigned short f2bf(float f) {
  unsigned u = __float_as_uint(f);
  unsigned r = (u + 0x7fffu + ((u >> 16) & 1u)) >> 16;
  return (unsigned short)r;
}
__device__ __forceinline__ float bf2f(unsigned short h) {
  return __uint_as_float(((unsigned)h) << 16);
}

__device__ __forceinline__ void gll16(const void* g, void* l) {
  __builtin_amdgcn_global_load_lds(
      (const __attribute__((address_space(1))) unsigned int*)g,
      (__attribute__((address_space(3))) unsigned int*)l, 16, 0, 0);
}

// ---- K0: fused row-norm + bf16 hi/lo split + min-buffer init + cnt zero ----
__global__ __launch_bounds__(256)
void k0_split(const float* __restrict__ E, unsigned short* __restrict__ hi,
              unsigned short* __restrict__ lo, float* __restrict__ sq,
              unsigned* __restrict__ minAll, unsigned* __restrict__ minSemi,
              int* __restrict__ cnt, int B) {
  if (blockIdx.x == 0) {
    for (int c = threadIdx.x; c < 512; c += 256) cnt[c] = 0;
  }
  int wave = threadIdx.x >> 6, lane = threadIdx.x & 63;
  int row = blockIdx.x * 4 + wave;
  if (row >= B) return;
  float4 v = *(const float4*)&E[(size_t)row * D + lane * 4];
  ushort4 h, l;
  h.x = f2bf(v.x); l.x = f2bf(v.x - bf2f(h.x));
  h.y = f2bf(v.y); l.y = f2bf(v.y - bf2f(h.y));
  h.z = f2bf(v.z); l.z = f2bf(v.z - bf2f(h.z));
  h.w = f2bf(v.w); l.w = f2bf(v.w - bf2f(h.w));
  *(ushort4*)&hi[(size_t)row * D + lane * 4] = h;
  *(ushort4*)&lo[(size_t)row * D + lane * 4] = l;
  float s = v.x * v.x + v.y * v.y + v.z * v.z + v.w * v.w;
#pragma unroll
  for (int off = 32; off; off >>= 1) s += __shfl_xor(s, off);
  if (lane == 0) {
    sq[row] = s;
    minAll[row] = __float_as_uint(BIGF);
    minSemi[row] = __float_as_uint(BIGF);
  }
}

// ---- KB: class buckets (order nondeterministic; max is order-independent) --
__global__ __launch_bounds__(256)
void kb_fill(const int* __restrict__ labels, int* __restrict__ cnt,
             int* __restrict__ members, int B) {
  int i = blockIdx.x * 256 + threadIdx.x;
  if (i >= B) return;
  int lab = labels[i];
  int p = atomicAdd(&cnt[lab], 1);
  if (p < MAXC) members[lab * MAXC + p] = i;
}

// ---- K1: hardest positive per row via bucket list (one wave per row) ----
__global__ __launch_bounds__(256)
void k1_dap(const float* __restrict__ E, const int* __restrict__ labels,
            const float* __restrict__ sq, const int* __restrict__ cnt,
            const int* __restrict__ members, float* __restrict__ d_ap,
            int* __restrict__ haspos, int B) {
  int wave = threadIdx.x >> 6, lane = threadIdx.x & 63;
  int i = blockIdx.x * 4 + wave;
  if (i >= B) return;
  float4 a = *(const float4*)&E[(size_t)i * D + lane * 4];
  int li = labels[i];
  int n = min(cnt[li], MAXC);
  float sqi = sq[i];
  float m = -BIGF;
  int p = 0;
  for (; p + 1 < n; p += 2) {
    int j0 = members[li * MAXC + p];
    int j1 = members[li * MAXC + p + 1];
    float4 b0 = *(const float4*)&E[(size_t)j0 * D + lane * 4];
    float4 b1 = *(const float4*)&E[(size_t)j1 * D + lane * 4];
    float s0 = a.x * b0.x + a.y * b0.y + a.z * b0.z + a.w * b0.w;
    float s1 = a.x * b1.x + a.y * b1.y + a.z * b1.z + a.w * b1.w;
#pragma unroll
    for (int off = 32; off; off >>= 1) {
      s0 += __shfl_xor(s0, off);
      s1 += __shfl_xor(s1, off);
    }
    float d0 = fmaxf(sqi + sq[j0] - 2.f * s0, 0.f);
    float d1 = fmaxf(sqi + sq[j1] - 2.f * s1, 0.f);
    if (j0 != i) m = fmaxf(m, d0);
    if (j1 != i) m = fmaxf(m, d1);
  }
  if (p < n) {
    int j = members[li * MAXC + p];
    if (j != i) {
      float4 b = *(const float4*)&E[(size_t)j * D + lane * 4];
      float s = a.x * b.x + a.y * b.y + a.z * b.z + a.w * b.w;
#pragma unroll
      for (int off = 32; off; off >>= 1) s += __shfl_xor(s, off);
      m = fmaxf(m, fmaxf(sqi + sq[j] - 2.f * s, 0.f));
    }
  }
  if (lane == 0) {
    d_ap[i] = (n > 1) ? m : -BIGF;
    haspos[i] = (n > 1) ? 1 : 0;
  }
}

// ---- K2: SYMMETRIC split-bf16 MFMA Gram, lower-triangle tiles -------------
// dot = hi*hi^T + hi*lo^T + lo*hi^T, one accumulator.
// T2 swizzle adapted to global_load_lds (m173): LDS dest linear, global
// SOURCE chunk permuted ch_src = ch_phys ^ (row&7); ds_read applies the same
// XOR -> 16 lanes cover all 8 chunks twice -> 2-way (free) instead of 16-way.
__global__ __launch_bounds__(256)
void k2_sym(const unsigned short* __restrict__ Ehi, const unsigned short* __restrict__ Elo,
            const float* __restrict__ sq, const float* __restrict__ d_ap,
            const int* __restrict__ labels,
            unsigned* __restrict__ minAll, unsigned* __restrict__ minSemi, int T) {
  __shared__ unsigned short Ah[128][64], Al[128][64], Bh[128][64], Bl[128][64];
  __shared__ float sqI[128], sqJ[128], dapI[128], dapJ[128];
  __shared__ int labI[128], labJ[128];
  __shared__ unsigned smAI[128], smSI[128], smAJ[128], smSJ[128];

  const int tid = threadIdx.x;
  const int lane = tid & 63;
  const int wave = tid >> 6;
  const int wr = wave >> 1, wc = wave & 1;
  const int lo4 = lane & 15, hi4 = lane >> 4;
  const int wbase = tid & 192;
  const int swc = lo4 & 7;  // fragment row & 7

  const int nwg = gridDim.x;
  const int bid = blockIdx.x;
  const int swz = ((nwg & 7) == 0) ? (bid & 7) * (nwg >> 3) + (bid >> 3) : bid;
  // triangle decode: swz = ti*(ti+1)/2 + tj, 0 <= tj <= ti < T
  int ti = (int)((sqrtf(8.f * (float)swz + 1.f) - 1.f) * 0.5f);
  while ((ti + 1) * (ti + 2) / 2 <= swz) ++ti;
  while (ti * (ti + 1) / 2 > swz) --ti;
  const int tj = swz - ti * (ti + 1) / 2;
  const int iBase = ti * 128, jBase = tj * 128;

  if (tid < 128) {
    int gi = iBase + tid, gj = jBase + tid;
    sqI[tid] = sq[gi]; labI[tid] = labels[gi]; dapI[tid] = d_ap[gi];
    sqJ[tid] = sq[gj]; labJ[tid] = labels[gj]; dapJ[tid] = d_ap[gj];
    smAI[tid] = smSI[tid] = smAJ[tid] = smSJ[tid] = __float_as_uint(BIGF);
  }

  f32x4 acc[4][4];
#pragma unroll
  for (int m = 0; m < 4; ++m)
#pragma unroll
    for (int n = 0; n < 4; ++n) acc[m][n] = (f32x4){0.f, 0.f, 0.f, 0.f};

  for (int kt = 0; kt < D / 64; ++kt) {
    const int k0 = kt * 64;
    __syncthreads();  // previous compute's LDS reads done
#pragma unroll
    for (int p = 0; p < 4; ++p) {
      int f = p * 256 + tid;
      int row = f >> 3;
      int chp = f & 7;
      int ch = chp ^ (row & 7);  // inverse swizzle on the per-lane source
      size_t sI = (size_t)(iBase + row) * D + k0 + ch * 8;
      size_t sJ = (size_t)(jBase + row) * D + k0 + ch * 8;
      size_t lOff = (size_t)(p * 256 + wbase) * 8;  // linear LDS dest (shorts)
      gll16(Ehi + sI, &Ah[0][0] + lOff);
      gll16(Elo + sI, &Al[0][0] + lOff);
      gll16(Ehi + sJ, &Bh[0][0] + lOff);
      gll16(Elo + sJ, &Bl[0][0] + lOff);
    }
    __syncthreads();  // vmcnt drained before barrier -> staged data visible
#pragma unroll
    for (int ks = 0; ks < 2; ++ks) {
      bf16x8 ah[4], al[4], bh[4], bl[4];
#pragma unroll
      for (int m = 0; m < 4; ++m) {
        const int col = (((ks << 2) | hi4) ^ swc) << 3;  // swizzled chunk * 8
        ah[m] = *(const bf16x8*)&Ah[wr * 64 + m * 16 + lo4][col];
        al[m] = *(const bf16x8*)&Al[wr * 64 + m * 16 + lo4][col];
      }
#pragma unroll
      for (int n = 0; n < 4; ++n) {
        const int col = (((ks << 2) | hi4) ^ swc) << 3;
        bh[n] = *(const bf16x8*)&Bh[wc * 64 + n * 16 + lo4][col];
        bl[n] = *(const bf16x8*)&Bl[wc * 64 + n * 16 + lo4][col];
      }
#pragma unroll
      for (int m = 0; m < 4; ++m)
#pragma unroll
        for (int n = 0; n < 4; ++n) {
          acc[m][n] = __builtin_amdgcn_mfma_f32_16x16x32_bf16(ah[m], bh[n], acc[m][n], 0, 0, 0);
          acc[m][n] = __builtin_amdgcn_mfma_f32_16x16x32_bf16(ah[m], bl[n], acc[m][n], 0, 0, 0);
          acc[m][n] = __builtin_amdgcn_mfma_f32_16x16x32_bf16(al[m], bh[n], acc[m][n], 0, 0, 0);
        }
    }
  }

  __syncthreads();
  // ---- row-side epilogue: anchors = i-rows, candidates = j-cols ----
#pragma unroll
  for (int m = 0; m < 4; ++m) {
#pragma unroll
    for (int reg = 0; reg < 4; ++reg) {
      const int li = wr * 64 + m * 16 + hi4 * 4 + reg;
      const float si = sqI[li], da = dapI[li];
      const int lbi = labI[li];
      float rA = BIGF, rS = BIGF;
#pragma unroll
      for (int n = 0; n < 4; ++n) {
        const int lj = wc * 64 + n * 16 + lo4;
        float dd = fmaxf(si + sqJ[lj] - 2.f * acc[m][n][reg], 0.f);
        if (labJ[lj] != lbi) {
          rA = fminf(rA, dd);
          if (dd > da && dd < da + MARGIN) rS = fminf(rS, dd);
        }
      }
#pragma unroll
      for (int off = 1; off < 16; off <<= 1) {
        rA = fminf(rA, __shfl_xor(rA, off));
        rS = fminf(rS, __shfl_xor(rS, off));
      }
      if (lo4 == 0) {
        atomicMin(&smAI[li], __float_as_uint(rA));
        atomicMin(&smSI[li], __float_as_uint(rS));
      }
    }
  }
  // ---- col-side epilogue: anchors = j-rows, candidates = i-cols ----
#pragma unroll
  for (int n = 0; n < 4; ++n) {
    const int lj = wc * 64 + n * 16 + lo4;
    const float sj = sqJ[lj], dj = dapJ[lj];
    const int lbj = labJ[lj];
    float cA = BIGF, cS = BIGF;
#pragma unroll
    for (int m = 0; m < 4; ++m)
#pragma unroll
      for (int reg = 0; reg < 4; ++reg) {
        const int li = wr * 64 + m * 16 + hi4 * 4 + reg;
        float dd = fmaxf(sqI[li] + sj - 2.f * acc[m][n][reg], 0.f);
        if (labI[li] != lbj) {
          cA = fminf(cA, dd);
          if (dd > dj && dd < dj + MARGIN) cS = fminf(cS, dd);
        }
      }
    cA = fminf(cA, __shfl_xor(cA, 16));
    cS = fminf(cS, __shfl_xor(cS, 16));
    cA = fminf(cA, __shfl_xor(cA, 32));
    cS = fminf(cS, __shfl_xor(cS, 32));
    if (hi4 == 0) {
      atomicMin(&smAJ[lj], __float_as_uint(cA));
      atomicMin(&smSJ[lj], __float_as_uint(cS));
    }
  }
  __syncthreads();
  if (tid < 128) {
    atomicMin(&minAll[iBase + tid], smAI[tid]);
    atomicMin(&minSemi[iBase + tid], smSI[tid]);
    atomicMin(&minAll[jBase + tid], smAJ[tid]);
    atomicMin(&minSemi[jBase + tid], smSJ[tid]);
  }
}

// ---- K3: deterministic final reduction ----
__global__ __launch_bounds__(1024)
void k3_final(const float* __restrict__ d_ap, const int* __restrict__ haspos,
              const unsigned* __restrict__ minAll, const unsigned* __restrict__ minSemi,
              float* __restrict__ out, int B) {
  __shared__ float ssum[1024];
  __shared__ int scnt[1024];
  int t = threadIdx.x;
  float lsum = 0.f;
  int lcnt = 0;
  for (int i = t; i < B; i += 1024) {
    float mA = __uint_as_float(minAll[i]);
    float mS = __uint_as_float(minSemi[i]);
    float dan = (mS < 1e29f) ? mS : mA;
    float loss = fmaxf(d_ap[i] - dan + MARGIN, 0.f);
    if (haspos[i]) { lsum += loss; lcnt += 1; }
  }
  ssum[t] = lsum;
  scnt[t] = lcnt;
  __syncthreads();
  for (int off = 512; off; off >>= 1) {
    if (t < off) { ssum[t] += ssum[t + off]; scnt[t] += scnt[t + off]; }
    __syncthreads();
  }
  if (t == 0) out[0] = ssum[0] / (float)max(scnt[0], 1);
}

extern "C" void kernel_launch(void* const* d_in, const int* in_sizes, int n_in,
                              void* d_out, int out_size, void* d_ws, size_t ws_size,
                              hipStream_t stream) {
  const float* E = (const float*)d_in[0];
  const int* labels = (const int*)d_in[1];
  int B = in_sizes[1];

  float* ws = (float*)d_ws;
  float* sq = ws;                                   // [B]
  float* dap = ws + B;                              // [B]
  int* haspos = (int*)(ws + 2 * B);                 // [B]
  unsigned* minAll = (unsigned*)(ws + 3 * B);       // [B]
  unsigned* minSemi = (unsigned*)(ws + 4 * B);      // [B]
  int* cnt = (int*)(ws + 5 * B);                    // [512]
  int* members = cnt + 512;                         // [512*MAXC]
  unsigned short* Ehi = (unsigned short*)(members + 512 * MAXC);  // [B*D] bf16
  unsigned short* Elo = Ehi + (size_t)B * D;                      // [B*D] bf16
  float* out = (float*)d_out;

  k0_split<<<(B + 3) / 4, 256, 0, stream>>>(E, Ehi, Elo, sq, minAll, minSemi, cnt, B);
  kb_fill<<<(B + 255) / 256, 256, 0, stream>>>(labels, cnt, members, B);
  k1_dap<<<(B + 3) / 4, 256, 0, stream>>>(E, labels, sq, cnt, members, dap, haspos, B);
  int T = B / 128;
  int nwg = T * (T + 1) / 2;
  k2_sym<<<nwg, 256, 0, stream>>>(Ehi, Elo, sq, dap, labels, minAll, minSemi, T);
  k3_final<<<1, 1024, 0, stream>>>(dap, haspos, minAll, minSemi, out, B);
}

// Round 5
// 114.600 us; speedup vs baseline: 5.5379x; 1.2955x over previous
//
#include <hip/hip_runtime.h>

#define MARGIN 0.3f
#define BIGF 1e30f
#define MAXC 64

constexpr int D = 256;

typedef __attribute__((ext_vector_type(8))) _Float16 f16x8;
typedef __attribute__((ext_vector_type(4))) _Float16 f16x4;
typedef __attribute__((ext_vector_type(4))) float f32x4;

__device__ __forceinline__ void gll16(const void* g, void* l) {
  __builtin_amdgcn_global_load_lds(
      (const __attribute__((address_space(1))) unsigned int*)g,
      (__attribute__((address_space(3))) unsigned int*)l, 16, 0, 0);
}

// ---- K0: fused row-norm + f16 convert + min-buffer init + cnt zero ----
__global__ __launch_bounds__(256)
void k0_prep(const float* __restrict__ E, _Float16* __restrict__ H,
             float* __restrict__ sq, unsigned* __restrict__ minAll,
             unsigned* __restrict__ minSemi, int* __restrict__ cnt, int B) {
  if (blockIdx.x == 0) {
    for (int c = threadIdx.x; c < 512; c += 256) cnt[c] = 0;
  }
  int wave = threadIdx.x >> 6, lane = threadIdx.x & 63;
  int row = blockIdx.x * 4 + wave;
  if (row >= B) return;
  float4 v = *(const float4*)&E[(size_t)row * D + lane * 4];
  f16x4 h;
  h.x = (_Float16)v.x; h.y = (_Float16)v.y;
  h.z = (_Float16)v.z; h.w = (_Float16)v.w;
  *(f16x4*)&H[(size_t)row * D + lane * 4] = h;
  float s = v.x * v.x + v.y * v.y + v.z * v.z + v.w * v.w;
#pragma unroll
  for (int off = 32; off; off >>= 1) s += __shfl_xor(s, off);
  if (lane == 0) {
    sq[row] = s;
    minAll[row] = __float_as_uint(BIGF);
    minSemi[row] = __float_as_uint(BIGF);
  }
}

// ---- KB: class buckets (order nondeterministic; max is order-independent) --
__global__ __launch_bounds__(256)
void kb_fill(const int* __restrict__ labels, int* __restrict__ cnt,
             int* __restrict__ members, int B) {
  int i = blockIdx.x * 256 + threadIdx.x;
  if (i >= B) return;
  int lab = labels[i];
  int p = atomicAdd(&cnt[lab], 1);
  if (p < MAXC) members[lab * MAXC + p] = i;
}

// ---- K1: hardest positive per row via bucket list (exact fp32 path) ----
__global__ __launch_bounds__(256)
void k1_dap(const float* __restrict__ E, const int* __restrict__ labels,
            const float* __restrict__ sq, const int* __restrict__ cnt,
            const int* __restrict__ members, float* __restrict__ d_ap,
            int* __restrict__ haspos, int B) {
  int wave = threadIdx.x >> 6, lane = threadIdx.x & 63;
  int i = blockIdx.x * 4 + wave;
  if (i >= B) return;
  float4 a = *(const float4*)&E[(size_t)i * D + lane * 4];
  int li = labels[i];
  int n = min(cnt[li], MAXC);
  float sqi = sq[i];
  float m = -BIGF;
  const int* mem = &members[li * MAXC];
  int p = 0;
  for (; p + 3 < n; p += 4) {
    int j0 = mem[p], j1 = mem[p + 1], j2 = mem[p + 2], j3 = mem[p + 3];
    float4 b0 = *(const float4*)&E[(size_t)j0 * D + lane * 4];
    float4 b1 = *(const float4*)&E[(size_t)j1 * D + lane * 4];
    float4 b2 = *(const float4*)&E[(size_t)j2 * D + lane * 4];
    float4 b3 = *(const float4*)&E[(size_t)j3 * D + lane * 4];
    float s0 = a.x * b0.x + a.y * b0.y + a.z * b0.z + a.w * b0.w;
    float s1 = a.x * b1.x + a.y * b1.y + a.z * b1.z + a.w * b1.w;
    float s2 = a.x * b2.x + a.y * b2.y + a.z * b2.z + a.w * b2.w;
    float s3 = a.x * b3.x + a.y * b3.y + a.z * b3.z + a.w * b3.w;
#pragma unroll
    for (int off = 32; off; off >>= 1) {
      s0 += __shfl_xor(s0, off);
      s1 += __shfl_xor(s1, off);
      s2 += __shfl_xor(s2, off);
      s3 += __shfl_xor(s3, off);
    }
    float d0 = fmaxf(sqi + sq[j0] - 2.f * s0, 0.f);
    float d1 = fmaxf(sqi + sq[j1] - 2.f * s1, 0.f);
    float d2 = fmaxf(sqi + sq[j2] - 2.f * s2, 0.f);
    float d3 = fmaxf(sqi + sq[j3] - 2.f * s3, 0.f);
    if (j0 != i) m = fmaxf(m, d0);
    if (j1 != i) m = fmaxf(m, d1);
    if (j2 != i) m = fmaxf(m, d2);
    if (j3 != i) m = fmaxf(m, d3);
  }
  for (; p < n; ++p) {
    int j = mem[p];
    if (j == i) continue;
    float4 b = *(const float4*)&E[(size_t)j * D + lane * 4];
    float s = a.x * b.x + a.y * b.y + a.z * b.z + a.w * b.w;
#pragma unroll
    for (int off = 32; off; off >>= 1) s += __shfl_xor(s, off);
    m = fmaxf(m, fmaxf(sqi + sq[j] - 2.f * s, 0.f));
  }
  if (lane == 0) {
    d_ap[i] = (n > 1) ? m : -BIGF;
    haspos[i] = (n > 1) ? 1 : 0;
  }
}

// ---- K2: f16 single-product symmetric MFMA Gram, lower-triangle tiles ----
// dot ~= H*H^T (H = f16(E)); dist2 error std ~0.009 vs 0.49 threshold.
// T2 swizzle via pre-swizzled global source (gll_lds dest stays linear);
// ds_read applies the same XOR -> conflict-free (verified R4: conflicts=0).
__global__ __launch_bounds__(256)
void k2_f16(const _Float16* __restrict__ H, const float* __restrict__ sq,
            const float* __restrict__ d_ap, const int* __restrict__ labels,
            unsigned* __restrict__ minAll, unsigned* __restrict__ minSemi, int T) {
  __shared__ _Float16 Ah[128][64], Bh[128][64];
  __shared__ float sqI[128], sqJ[128], dapI[128], dapJ[128];
  __shared__ int labI[128], labJ[128];
  __shared__ unsigned smAI[128], smSI[128], smAJ[128], smSJ[128];

  const int tid = threadIdx.x;
  const int lane = tid & 63;
  const int wave = tid >> 6;
  const int wr = wave >> 1, wc = wave & 1;
  const int lo4 = lane & 15, hi4 = lane >> 4;
  const int wbase = tid & 192;
  const int swc = lo4 & 7;

  const int nwg = gridDim.x;
  const int bid = blockIdx.x;
  const int swz = ((nwg & 7) == 0) ? (bid & 7) * (nwg >> 3) + (bid >> 3) : bid;
  int ti = (int)((sqrtf(8.f * (float)swz + 1.f) - 1.f) * 0.5f);
  while ((ti + 1) * (ti + 2) / 2 <= swz) ++ti;
  while (ti * (ti + 1) / 2 > swz) --ti;
  const int tj = swz - ti * (ti + 1) / 2;
  const int iBase = ti * 128, jBase = tj * 128;

  if (tid < 128) {
    int gi = iBase + tid, gj = jBase + tid;
    sqI[tid] = sq[gi]; labI[tid] = labels[gi]; dapI[tid] = d_ap[gi];
    sqJ[tid] = sq[gj]; labJ[tid] = labels[gj]; dapJ[tid] = d_ap[gj];
    smAI[tid] = smSI[tid] = smAJ[tid] = smSJ[tid] = __float_as_uint(BIGF);
  }

  f32x4 acc[4][4];
#pragma unroll
  for (int m = 0; m < 4; ++m)
#pragma unroll
    for (int n = 0; n < 4; ++n) acc[m][n] = (f32x4){0.f, 0.f, 0.f, 0.f};

  for (int kt = 0; kt < D / 64; ++kt) {
    const int k0 = kt * 64;
    __syncthreads();  // previous compute's LDS reads done
#pragma unroll
    for (int p = 0; p < 4; ++p) {
      int f = p * 256 + tid;
      int row = f >> 3;
      int chp = f & 7;
      int ch = chp ^ (row & 7);  // inverse swizzle on the per-lane source
      size_t sI = (size_t)(iBase + row) * D + k0 + ch * 8;
      size_t sJ = (size_t)(jBase + row) * D + k0 + ch * 8;
      size_t lOff = (size_t)(p * 256 + wbase) * 8;  // linear LDS dest (f16 units)
      gll16(H + sI, &Ah[0][0] + lOff);
      gll16(H + sJ, &Bh[0][0] + lOff);
    }
    __syncthreads();  // vmcnt drained before barrier -> staged data visible
#pragma unroll
    for (int ks = 0; ks < 2; ++ks) {
      f16x8 aF[4], bF[4];
#pragma unroll
      for (int m = 0; m < 4; ++m) {
        const int col = (((ks << 2) | hi4) ^ swc) << 3;
        aF[m] = *(const f16x8*)&Ah[wr * 64 + m * 16 + lo4][col];
      }
#pragma unroll
      for (int n = 0; n < 4; ++n) {
        const int col = (((ks << 2) | hi4) ^ swc) << 3;
        bF[n] = *(const f16x8*)&Bh[wc * 64 + n * 16 + lo4][col];
      }
#pragma unroll
      for (int m = 0; m < 4; ++m)
#pragma unroll
        for (int n = 0; n < 4; ++n)
          acc[m][n] = __builtin_amdgcn_mfma_f32_16x16x32_f16(aF[m], bF[n], acc[m][n], 0, 0, 0);
    }
  }

  __syncthreads();
  // ---- row-side epilogue: anchors = i-rows, candidates = j-cols ----
#pragma unroll
  for (int m = 0; m < 4; ++m) {
#pragma unroll
    for (int reg = 0; reg < 4; ++reg) {
      const int li = wr * 64 + m * 16 + hi4 * 4 + reg;
      const float si = sqI[li], da = dapI[li];
      const int lbi = labI[li];
      float rA = BIGF, rS = BIGF;
#pragma unroll
      for (int n = 0; n < 4; ++n) {
        const int lj = wc * 64 + n * 16 + lo4;
        float dd = fmaxf(si + sqJ[lj] - 2.f * acc[m][n][reg], 0.f);
        if (labJ[lj] != lbi) {
          rA = fminf(rA, dd);
          if (dd > da && dd < da + MARGIN) rS = fminf(rS, dd);
        }
      }
#pragma unroll
      for (int off = 1; off < 16; off <<= 1) {
        rA = fminf(rA, __shfl_xor(rA, off));
        rS = fminf(rS, __shfl_xor(rS, off));
      }
      if (lo4 == 0) {
        atomicMin(&smAI[li], __float_as_uint(rA));
        atomicMin(&smSI[li], __float_as_uint(rS));
      }
    }
  }
  // ---- col-side epilogue: anchors = j-rows, candidates = i-cols ----
#pragma unroll
  for (int n = 0; n < 4; ++n) {
    const int lj = wc * 64 + n * 16 + lo4;
    const float sj = sqJ[lj], dj = dapJ[lj];
    const int lbj = labJ[lj];
    float cA = BIGF, cS = BIGF;
#pragma unroll
    for (int m = 0; m < 4; ++m)
#pragma unroll
      for (int reg = 0; reg < 4; ++reg) {
        const int li = wr * 64 + m * 16 + hi4 * 4 + reg;
        float dd = fmaxf(sqI[li] + sj - 2.f * acc[m][n][reg], 0.f);
        if (labI[li] != lbj) {
          cA = fminf(cA, dd);
          if (dd > dj && dd < dj + MARGIN) cS = fminf(cS, dd);
        }
      }
    cA = fminf(cA, __shfl_xor(cA, 16));
    cS = fminf(cS, __shfl_xor(cS, 16));
    cA = fminf(cA, __shfl_xor(cA, 32));
    cS = fminf(cS, __shfl_xor(cS, 32));
    if (hi4 == 0) {
      atomicMin(&smAJ[lj], __float_as_uint(cA));
      atomicMin(&smSJ[lj], __float_as_uint(cS));
    }
  }
  __syncthreads();
  if (tid < 128) {
    atomicMin(&minAll[iBase + tid], smAI[tid]);
    atomicMin(&minSemi[iBase + tid], smSI[tid]);
    atomicMin(&minAll[jBase + tid], smAJ[tid]);
    atomicMin(&minSemi[jBase + tid], smSJ[tid]);
  }
}

// ---- K3: deterministic final reduction ----
__global__ __launch_bounds__(1024)
void k3_final(const float* __restrict__ d_ap, const int* __restrict__ haspos,
              const unsigned* __restrict__ minAll, const unsigned* __restrict__ minSemi,
              float* __restrict__ out, int B) {
  __shared__ float ssum[1024];
  __shared__ int scnt[1024];
  int t = threadIdx.x;
  float lsum = 0.f;
  int lcnt = 0;
  for (int i = t; i < B; i += 1024) {
    float mA = __uint_as_float(minAll[i]);
    float mS = __uint_as_float(minSemi[i]);
    float dan = (mS < 1e29f) ? mS : mA;
    float loss = fmaxf(d_ap[i] - dan + MARGIN, 0.f);
    if (haspos[i]) { lsum += loss; lcnt += 1; }
  }
  ssum[t] = lsum;
  scnt[t] = lcnt;
  __syncthreads();
  for (int off = 512; off; off >>= 1) {
    if (t < off) { ssum[t] += ssum[t + off]; scnt[t] += scnt[t + off]; }
    __syncthreads();
  }
  if (t == 0) out[0] = ssum[0] / (float)max(scnt[0], 1);
}

extern "C" void kernel_launch(void* const* d_in, const int* in_sizes, int n_in,
                              void* d_out, int out_size, void* d_ws, size_t ws_size,
                              hipStream_t stream) {
  const float* E = (const float*)d_in[0];
  const int* labels = (const int*)d_in[1];
  int B = in_sizes[1];

  float* ws = (float*)d_ws;
  float* sq = ws;                                   // [B]
  float* dap = ws + B;                              // [B]
  int* haspos = (int*)(ws + 2 * B);                 // [B]
  unsigned* minAll = (unsigned*)(ws + 3 * B);       // [B]
  unsigned* minSemi = (unsigned*)(ws + 4 * B);      // [B]
  int* cnt = (int*)(ws + 5 * B);                    // [512]
  int* members = cnt + 512;                         // [512*MAXC]
  _Float16* H = (_Float16*)(members + 512 * MAXC);  // [B*D] f16
  float* out = (float*)d_out;

  k0_prep<<<(B + 3) / 4, 256, 0, stream>>>(E, H, sq, minAll, minSemi, cnt, B);
  kb_fill<<<(B + 255) / 256, 256, 0, stream>>>(labels, cnt, members, B);
  k1_dap<<<(B + 3) / 4, 256, 0, stream>>>(E, labels, sq, cnt, members, dap, haspos, B);
  int T = B / 128;
  int nwg = T * (T + 1) / 2;
  k2_f16<<<nwg, 256, 0, stream>>>(H, sq, dap, labels, minAll, minSemi, T);
  k3_final<<<1, 1024, 0, stream>>>(dap, haspos, minAll, minSemi, out, B);
}